// Round 1
// baseline (6598.868 us; speedup 1.0000x reference)
//
#include <hip/hip_runtime.h>
#include <math.h>

#define BATCH 4
#define NPB   4096      // pixels per batch (H*W)
#define BN    16384     // BATCH * NPB
#define CC    256       // input channels
#define CPV   128       // output channels (C/2)

// ---------------------------------------------------------------------------
// Projection kernel: computes K, Q, V, shortcut = x @ W* + b* for all pixels.
// Tile: 16 pixels x all 512 outputs per block (256 threads, 2 outputs each).
// ---------------------------------------------------------------------------
__global__ __launch_bounds__(256) void proj_kernel(
    const float* __restrict__ x,
    const float* __restrict__ Wk, const float* __restrict__ bk,
    const float* __restrict__ Wq, const float* __restrict__ bq,
    const float* __restrict__ Wv, const float* __restrict__ bv,
    const float* __restrict__ Ws, const float* __restrict__ bs,
    float* __restrict__ outK, float* __restrict__ outQ,
    float* __restrict__ outV, float* __restrict__ outS)
{
    __shared__ __align__(16) float xs[16 * 256];   // 16 KB
    const int tid  = threadIdx.x;
    const int row0 = blockIdx.x * 16;

    // stage 16 rows of x (16*256 floats = 1024 float4), coalesced
    const float4* xg  = (const float4*)(x + (size_t)row0 * CC);
    float4*       xs4 = (float4*)xs;
    for (int i = tid; i < 1024; i += 256) xs4[i] = xg[i];
    __syncthreads();

    const int c  = tid & 127;
    const int m1 = tid >> 7;                 // 0 -> (K,V), 1 -> (Q,S)
    const float* W1 = (m1 == 0) ? Wk : Wq;
    const float* W2 = (m1 == 0) ? Wv : Ws;
    const float* B1 = (m1 == 0) ? bk : bq;
    const float* B2 = (m1 == 0) ? bv : bs;

    float acc1[16], acc2[16];
#pragma unroll
    for (int p = 0; p < 16; ++p) { acc1[p] = 0.f; acc2[p] = 0.f; }

    for (int k = 0; k < 256; k += 4) {
        const float w1a = W1[(k + 0) * CPV + c];
        const float w1b = W1[(k + 1) * CPV + c];
        const float w1c = W1[(k + 2) * CPV + c];
        const float w1d = W1[(k + 3) * CPV + c];
        const float w2a = W2[(k + 0) * CPV + c];
        const float w2b = W2[(k + 1) * CPV + c];
        const float w2c = W2[(k + 2) * CPV + c];
        const float w2d = W2[(k + 3) * CPV + c];
#pragma unroll
        for (int p = 0; p < 16; ++p) {
            const float4 xv = *(const float4*)&xs[p * 256 + k];
            acc1[p] = fmaf(xv.x, w1a, acc1[p]);
            acc1[p] = fmaf(xv.y, w1b, acc1[p]);
            acc1[p] = fmaf(xv.z, w1c, acc1[p]);
            acc1[p] = fmaf(xv.w, w1d, acc1[p]);
            acc2[p] = fmaf(xv.x, w2a, acc2[p]);
            acc2[p] = fmaf(xv.y, w2b, acc2[p]);
            acc2[p] = fmaf(xv.z, w2c, acc2[p]);
            acc2[p] = fmaf(xv.w, w2d, acc2[p]);
        }
    }

    const float b1 = B1[c], b2 = B2[c];
    float* O1 = (m1 == 0) ? outK : outQ;
    float* O2 = (m1 == 0) ? outV : outS;
#pragma unroll
    for (int p = 0; p < 16; ++p) {
        O1[(size_t)(row0 + p) * CPV + c] = acc1[p] + b1;
        O2[(size_t)(row0 + p) * CPV + c] = acc2[p] + b2;
    }
}

// ---------------------------------------------------------------------------
// Attention kernel: one block (256 threads) per output row r.
//   out[r, c] = ( sum_m softmax_m(K[r].Q[m]) * V[m, c] ) + shortcut[r, c]
// Scores for the whole row (4096) live in LDS.
// ---------------------------------------------------------------------------
__global__ __launch_bounds__(256) void attn_kernel(
    const float* __restrict__ Kp, const float* __restrict__ Qp,
    const float* __restrict__ Vp, const float* __restrict__ Sp,
    float* __restrict__ out)
{
    __shared__ __align__(16) float sc[NPB];    // 16 KB scores
    __shared__ __align__(16) float kn[CPV];    // K row
    __shared__ float redm[5];
    __shared__ float reds[5];
    __shared__ float pout[CPV];

    const int tid = threadIdx.x;
    const int r   = blockIdx.x;
    const int rb  = (r >> 12) << 12;           // batch base row (r/4096*4096)

    if (tid < 32)
        ((float4*)kn)[tid] = ((const float4*)(Kp + (size_t)r * CPV))[tid];
    __syncthreads();

    // ---- Phase 1: scores + local max (2 rows per iteration to amortize kn reads)
    const float4* k4 = (const float4*)kn;
    float lmax = -INFINITY;
    for (int m = tid; m < NPB; m += 512) {
        const int m2 = m + 256;
        const float4* qa = (const float4*)(Qp + (size_t)(rb + m)  * CPV);
        const float4* qb = (const float4*)(Qp + (size_t)(rb + m2) * CPV);
        float da = 0.f, db = 0.f;
#pragma unroll
        for (int i = 0; i < 32; ++i) {
            const float4 kk = k4[i];
            const float4 a  = qa[i];
            const float4 b  = qb[i];
            da = fmaf(kk.x, a.x, da); da = fmaf(kk.y, a.y, da);
            da = fmaf(kk.z, a.z, da); da = fmaf(kk.w, a.w, da);
            db = fmaf(kk.x, b.x, db); db = fmaf(kk.y, b.y, db);
            db = fmaf(kk.z, b.z, db); db = fmaf(kk.w, b.w, db);
        }
        sc[m]  = da;
        sc[m2] = db;
        lmax = fmaxf(lmax, fmaxf(da, db));
    }

    // ---- block-reduce max
    for (int off = 32; off > 0; off >>= 1)
        lmax = fmaxf(lmax, __shfl_down(lmax, off));
    if ((tid & 63) == 0) redm[tid >> 6] = lmax;
    __syncthreads();
    if (tid == 0)
        redm[4] = fmaxf(fmaxf(redm[0], redm[1]), fmaxf(redm[2], redm[3]));
    __syncthreads();
    const float gmax = redm[4];

    // ---- exp + local sum
    float lsum = 0.f;
    for (int m = tid; m < NPB; m += 256) {
        const float p = __expf(sc[m] - gmax);
        sc[m] = p;
        lsum += p;
    }
    for (int off = 32; off > 0; off >>= 1)
        lsum += __shfl_down(lsum, off);
    if ((tid & 63) == 0) reds[tid >> 6] = lsum;
    __syncthreads();
    if (tid == 0)
        reds[4] = reds[0] + reds[1] + reds[2] + reds[3];
    __syncthreads();
    const float inv = 1.0f / reds[4];

    // ---- Phase 2: out[c] = sum_m p[m] * V[m, c]  (split m range over 2 halves)
    const int c    = tid & 127;
    const int half = tid >> 7;
    const float* vb = Vp + (size_t)rb * CPV + c;
    float acc = 0.f;
    const int m0 = half * 2048;
    for (int m = m0; m < m0 + 2048; m += 4) {
        const float4 p4 = *(const float4*)&sc[m];
        acc = fmaf(p4.x, vb[(size_t)(m + 0) * CPV], acc);
        acc = fmaf(p4.y, vb[(size_t)(m + 1) * CPV], acc);
        acc = fmaf(p4.z, vb[(size_t)(m + 2) * CPV], acc);
        acc = fmaf(p4.w, vb[(size_t)(m + 3) * CPV], acc);
    }
    if (half) pout[c] = acc;
    __syncthreads();
    if (!half) {
        const float tot = (acc + pout[c]) * inv;
        out[(size_t)r * CPV + c] = tot + Sp[(size_t)r * CPV + c];
    }
}

extern "C" void kernel_launch(void* const* d_in, const int* in_sizes, int n_in,
                              void* d_out, int out_size, void* d_ws, size_t ws_size,
                              hipStream_t stream) {
    const float* x  = (const float*)d_in[0];
    const float* Wk = (const float*)d_in[1];
    const float* bk = (const float*)d_in[2];
    const float* Wq = (const float*)d_in[3];
    const float* bq = (const float*)d_in[4];
    const float* Wv = (const float*)d_in[5];
    const float* bv = (const float*)d_in[6];
    const float* Ws = (const float*)d_in[7];
    const float* bs = (const float*)d_in[8];
    float* out = (float*)d_out;

    float* ws = (float*)d_ws;
    const size_t seg = (size_t)BN * CPV;   // 2,097,152 floats per matrix
    float* Kp = ws;
    float* Qp = ws + seg;
    float* Vp = ws + 2 * seg;
    float* Sp = ws + 3 * seg;              // total 32 MB of workspace

    proj_kernel<<<BN / 16, 256, 0, stream>>>(x, Wk, bk, Wq, bq, Wv, bv, Ws, bs,
                                             Kp, Qp, Vp, Sp);
    attn_kernel<<<BN, 256, 0, stream>>>(Kp, Qp, Vp, Sp, out);
}

// Round 2
// 277.368 us; speedup vs baseline: 23.7910x; 23.7910x over previous
//
#include <hip/hip_runtime.h>
#include <math.h>

typedef unsigned short u16;
typedef __attribute__((ext_vector_type(8))) short short8;
typedef __attribute__((ext_vector_type(4))) float f32x4;

#define BATCH 4
#define NPB   4096      // pixels per batch (H*W)
#define BN    16384     // BATCH * NPB
#define CC    256       // input channels
#define D     128       // output channels (C/2)

__device__ __forceinline__ u16 f2bf(float f) {
    unsigned u = __builtin_bit_cast(unsigned, f);
    u += 0x7fff + ((u >> 16) & 1);          // round-to-nearest-even
    return (u16)(u >> 16);
}

// ---------------------------------------------------------------------------
// Projection: K,Q -> bf16 row-major [n][128]; V -> bf16 transposed [b][c][m];
// shortcut -> fp32 [n][128].
// ---------------------------------------------------------------------------
__global__ __launch_bounds__(256) void proj_kernel(
    const float* __restrict__ x,
    const float* __restrict__ Wk, const float* __restrict__ bk,
    const float* __restrict__ Wq, const float* __restrict__ bq,
    const float* __restrict__ Wv, const float* __restrict__ bv,
    const float* __restrict__ Ws, const float* __restrict__ bs,
    u16* __restrict__ Kb, u16* __restrict__ Qb,
    u16* __restrict__ Vtg, float* __restrict__ Sc)
{
    __shared__ __align__(16) float xs[16 * 256];   // 16 KB
    __shared__ __align__(16) float vt[128][16];    // 8 KB (V transpose staging)
    const int tid  = threadIdx.x;
    const int row0 = blockIdx.x * 16;

    const float4* xg  = (const float4*)(x + (size_t)row0 * CC);
    float4*       xs4 = (float4*)xs;
    for (int i = tid; i < 1024; i += 256) xs4[i] = xg[i];
    __syncthreads();

    const int c  = tid & 127;
    const int m1 = tid >> 7;                 // 0 -> (K,V), 1 -> (Q,S)
    const float* W1 = m1 ? Wq : Wk;
    const float* W2 = m1 ? Ws : Wv;
    const float* B1 = m1 ? bq : bk;
    const float* B2 = m1 ? bs : bv;

    float acc1[16], acc2[16];
#pragma unroll
    for (int p = 0; p < 16; ++p) { acc1[p] = 0.f; acc2[p] = 0.f; }

    for (int k = 0; k < 256; k += 4) {
        const float w1a = W1[(k + 0) * D + c];
        const float w1b = W1[(k + 1) * D + c];
        const float w1c = W1[(k + 2) * D + c];
        const float w1d = W1[(k + 3) * D + c];
        const float w2a = W2[(k + 0) * D + c];
        const float w2b = W2[(k + 1) * D + c];
        const float w2c = W2[(k + 2) * D + c];
        const float w2d = W2[(k + 3) * D + c];
#pragma unroll
        for (int p = 0; p < 16; ++p) {
            const float4 xv = *(const float4*)&xs[p * 256 + k];
            acc1[p] = fmaf(xv.x, w1a, acc1[p]);
            acc1[p] = fmaf(xv.y, w1b, acc1[p]);
            acc1[p] = fmaf(xv.z, w1c, acc1[p]);
            acc1[p] = fmaf(xv.w, w1d, acc1[p]);
            acc2[p] = fmaf(xv.x, w2a, acc2[p]);
            acc2[p] = fmaf(xv.y, w2b, acc2[p]);
            acc2[p] = fmaf(xv.z, w2c, acc2[p]);
            acc2[p] = fmaf(xv.w, w2d, acc2[p]);
        }
    }

    const float b1 = B1[c], b2 = B2[c];
    if (m1 == 0) {
#pragma unroll
        for (int p = 0; p < 16; ++p) {
            Kb[(size_t)(row0 + p) * D + c] = f2bf(acc1[p] + b1);
            vt[c][p] = acc2[p] + b2;
        }
    } else {
#pragma unroll
        for (int p = 0; p < 16; ++p) {
            Qb[(size_t)(row0 + p) * D + c] = f2bf(acc1[p] + b1);
            Sc[(size_t)(row0 + p) * D + c] = acc2[p] + b2;
        }
    }
    __syncthreads();

    // transpose-write V: thread t -> c-row t>>1, half t&1 (8 m values, 16 B)
    const int c2 = tid >> 1, hf = tid & 1;
    const int batch = row0 >> 12, m = row0 & 4095;
    u16 tmp[8];
#pragma unroll
    for (int i = 0; i < 8; ++i) tmp[i] = f2bf(vt[c2][hf * 8 + i]);
    *(uint4*)&Vtg[(size_t)batch * (NPB * D) + (size_t)c2 * NPB + m + hf * 8] =
        *(const uint4*)tmp;
}

// ---------------------------------------------------------------------------
// Flash attention: 512 blocks, 32 n-rows each. 4 waves = 2 n-groups x 2
// m-halves; each wave online-softmaxes its own 2048-m range in Tm=32 tiles
// using 16x16x32 bf16 MFMA; cross-wave combine at the end.
// ---------------------------------------------------------------------------
#define TM 32
#define QP 136          // Qs/Ks row pitch (u16), 272 B -> 4-bank row shift
#define VP 40           // Vs/Ps row pitch (u16),  80 B -> 4-bank row shift

__global__ __launch_bounds__(256) void attn_kernel(
    const u16* __restrict__ Kb, const u16* __restrict__ Qb,
    const u16* __restrict__ Vt, const float* __restrict__ Sc,
    float* __restrict__ out)
{
    __shared__ __align__(16) unsigned char smem[51712];
    u16 (*Ks)[QP]     = (u16(*)[QP])(smem);                 // 32 x 136 (8704 B)
    u16 (*Qs)[TM][QP] = (u16(*)[TM][QP])(smem + 8704);      // 2 x 32 x 136 (17408 B)
    u16 (*Vs)[D][VP]  = (u16(*)[D][VP])(smem + 26112);      // 2 x 128 x 40 (20480 B)
    u16 (*Ps)[16][VP] = (u16(*)[16][VP])(smem + 46592);     // 4 x 16 x 40 (5120 B)

    const int tid = threadIdx.x;
    const int wv  = tid >> 6;
    const int l   = tid & 63;
    const int l15 = l & 15;
    const int l4  = l >> 4;
    const int batch = blockIdx.x & 3;       // XCD/L2 locality: batch per XCD pair
    const int tile  = blockIdx.x >> 2;
    const int gr0   = batch * NPB + tile * 32;

    const int n16 = wv & 1;                 // which 16-row group
    const int mh  = wv >> 1;                // which m-half

    // ---- stage K tile (32 x 128 -> padded LDS)
    {
        const int row = tid >> 3, ch = tid & 7;
        const uint4* src = (const uint4*)(Kb + (size_t)(gr0 + row) * D + ch * 16);
        *(uint4*)&Ks[row][ch * 16]     = src[0];
        *(uint4*)&Ks[row][ch * 16 + 8] = src[1];
    }
    __syncthreads();

    short8 kf[4];
#pragma unroll
    for (int kc = 0; kc < 4; ++kc)
        kf[kc] = *(const short8*)&Ks[n16 * 16 + l15][kc * 32 + l4 * 8];

    f32x4 Oc[8];
#pragma unroll
    for (int ct = 0; ct < 8; ++ct) Oc[ct] = (f32x4){0.f, 0.f, 0.f, 0.f};
    float mold[4], lsum[4];
#pragma unroll
    for (int r = 0; r < 4; ++r) { mold[r] = -1e30f; lsum[r] = 0.f; }

    const u16* qsrc = Qb + (size_t)(batch * NPB + wv * 2048) * D;   // wv<2 only
    const u16* vsrc = Vt + (size_t)batch * NPB * D;                 // c-major

    for (int it = 0; it < 64; ++it) {
        __syncthreads();
        const int m0 = it * TM;
        if (wv < 2) {
            // stage Qs[wv]: 32 rows x 256 B, 8 chunks of 4 rows
            const u16* s = qsrc + (size_t)m0 * D + l15 * 8;
#pragma unroll
            for (int j = 0; j < 8; ++j) {
                const int row = j * 4 + l4;
                const uint4 v = *(const uint4*)(s + (size_t)row * D);
                *(uint4*)&Qs[wv][row][l15 * 8] = v;
            }
        } else {
            const int h = wv - 2;
            const u16* s = vsrc + (size_t)(h * 2048 + m0) + (l & 3) * 8;
#pragma unroll
            for (int j = 0; j < 8; ++j) {
                const int cc = j * 16 + (l >> 2);
                const uint4 v = *(const uint4*)(s + (size_t)cc * NPB);
                *(uint4*)&Vs[h][cc][(l & 3) * 8] = v;
            }
        }
        __syncthreads();

        // ---- S = K @ Q^T (16 n x 32 m per wave)
        f32x4 sacc[2];
        sacc[0] = (f32x4){0.f, 0.f, 0.f, 0.f};
        sacc[1] = (f32x4){0.f, 0.f, 0.f, 0.f};
#pragma unroll
        for (int kc = 0; kc < 4; ++kc) {
#pragma unroll
            for (int mt = 0; mt < 2; ++mt) {
                const short8 qf =
                    *(const short8*)&Qs[mh][mt * 16 + l15][kc * 32 + l4 * 8];
                sacc[mt] = __builtin_amdgcn_mfma_f32_16x16x32_bf16(
                    kf[kc], qf, sacc[mt], 0, 0, 0);
            }
        }

        // ---- online softmax (rows = l4*4+r, cols = mt*16 + l15)
        float rmax[4], rsum[4], pv0[4], pv1[4];
#pragma unroll
        for (int r = 0; r < 4; ++r) rmax[r] = fmaxf(sacc[0][r], sacc[1][r]);
#pragma unroll
        for (int mask = 1; mask <= 8; mask <<= 1)
#pragma unroll
            for (int r = 0; r < 4; ++r)
                rmax[r] = fmaxf(rmax[r], __shfl_xor(rmax[r], mask, 64));
#pragma unroll
        for (int r = 0; r < 4; ++r) {
            const float mnew  = fmaxf(mold[r], rmax[r]);
            const float alpha = __expf(mold[r] - mnew);
            mold[r] = mnew;
            const float s0 = __expf(sacc[0][r] - mnew);
            const float s1 = __expf(sacc[1][r] - mnew);
            pv0[r] = s0; pv1[r] = s1;
            rsum[r] = s0 + s1;
            lsum[r] *= alpha;
#pragma unroll
            for (int ct = 0; ct < 8; ++ct) Oc[ct][r] *= alpha;
        }
#pragma unroll
        for (int mask = 1; mask <= 8; mask <<= 1)
#pragma unroll
            for (int r = 0; r < 4; ++r)
                rsum[r] += __shfl_xor(rsum[r], mask, 64);
#pragma unroll
        for (int r = 0; r < 4; ++r) lsum[r] += rsum[r];

        // ---- P -> LDS (wave-local transpose to A-operand layout)
#pragma unroll
        for (int r = 0; r < 4; ++r) {
            Ps[wv][l4 * 4 + r][l15]      = f2bf(pv0[r]);
            Ps[wv][l4 * 4 + r][16 + l15] = f2bf(pv1[r]);
        }
        asm volatile("s_waitcnt lgkmcnt(0)" ::: "memory");

        const short8 pf = *(const short8*)&Ps[wv][l15][l4 * 8];
#pragma unroll
        for (int ct = 0; ct < 8; ++ct) {
            const short8 vf = *(const short8*)&Vs[mh][ct * 16 + l15][l4 * 8];
            Oc[ct] = __builtin_amdgcn_mfma_f32_16x16x32_bf16(pf, vf, Oc[ct], 0, 0, 0);
        }
    }

    // ---- combine the two m-halves (waves wv and wv^2 share rows)
    __syncthreads();
    float (*Obuf)[16][D] = (float(*)[16][D])(smem);         // aliases Ks/Qs
    float* cmbM = (float*)(smem + 26112);                   // aliases Vs
    float* cmbL = (float*)(smem + 26368);

    if (l15 == 0) {
#pragma unroll
        for (int r = 0; r < 4; ++r) {
            cmbM[wv * 16 + l4 * 4 + r] = mold[r];
            cmbL[wv * 16 + l4 * 4 + r] = lsum[r];
        }
    }
    if (mh == 1) {
#pragma unroll
        for (int ct = 0; ct < 8; ++ct)
#pragma unroll
            for (int r = 0; r < 4; ++r)
                Obuf[n16][l4 * 4 + r][ct * 16 + l15] = Oc[ct][r];
    }
    __syncthreads();

    if (mh == 0) {
        float f0[4], f1[4], invL[4];
#pragma unroll
        for (int r = 0; r < 4; ++r) {
            const int row = l4 * 4 + r;
            const float M1 = cmbM[(wv + 2) * 16 + row];
            const float L1 = cmbL[(wv + 2) * 16 + row];
            const float M  = fmaxf(mold[r], M1);
            const float a0 = __expf(mold[r] - M);
            const float a1 = __expf(M1 - M);
            f0[r] = a0; f1[r] = a1;
            invL[r] = 1.f / (lsum[r] * a0 + L1 * a1);
        }
#pragma unroll
        for (int ct = 0; ct < 8; ++ct) {
#pragma unroll
            for (int r = 0; r < 4; ++r) {
                const int row  = l4 * 4 + r;
                const int c    = ct * 16 + l15;
                const int grow = gr0 + n16 * 16 + row;
                const float val =
                    (Oc[ct][r] * f0[r] + Obuf[n16][row][c] * f1[r]) * invL[r]
                    + Sc[(size_t)grow * D + c];
                out[(size_t)grow * D + c] = val;
            }
        }
    }
}

extern "C" void kernel_launch(void* const* d_in, const int* in_sizes, int n_in,
                              void* d_out, int out_size, void* d_ws, size_t ws_size,
                              hipStream_t stream) {
    const float* x  = (const float*)d_in[0];
    const float* Wk = (const float*)d_in[1];
    const float* bk = (const float*)d_in[2];
    const float* Wq = (const float*)d_in[3];
    const float* bq = (const float*)d_in[4];
    const float* Wv = (const float*)d_in[5];
    const float* bv = (const float*)d_in[6];
    const float* Ws = (const float*)d_in[7];
    const float* bs = (const float*)d_in[8];
    float* out = (float*)d_out;

    u16*   Kb  = (u16*)d_ws;                       // 4 MB
    u16*   Qb  = Kb + (size_t)BN * D;              // 4 MB
    u16*   Vtg = Qb + (size_t)BN * D;              // 4 MB (transposed [b][c][m])
    float* Sc  = (float*)(Vtg + (size_t)BN * D);   // 8 MB

    proj_kernel<<<BN / 16, 256, 0, stream>>>(x, Wk, bk, Wq, bq, Wv, bv, Ws, bs,
                                             Kb, Qb, Vtg, Sc);
    attn_kernel<<<512, 256, 0, stream>>>(Kb, Qb, Vtg, Sc, out);
}

// Round 4
// 230.514 us; speedup vs baseline: 28.6268x; 1.2033x over previous
//
#include <hip/hip_runtime.h>
#include <math.h>

typedef unsigned short u16;
typedef __attribute__((ext_vector_type(8))) short    short8;   // 8 bf16
typedef __attribute__((ext_vector_type(8))) _Float16 half8;    // 8 fp16
typedef __attribute__((ext_vector_type(4))) float    f32x4;

#define BATCH 4
#define NPB   4096      // pixels per batch (H*W)
#define BN    16384     // BATCH * NPB
#define CC    256       // input channels
#define D     128       // output channels (C/2)

__device__ __forceinline__ u16 f2bf(float f) {
    unsigned u = __builtin_bit_cast(unsigned, f);
    u += 0x7fff + ((u >> 16) & 1);          // round-to-nearest-even
    return (u16)(u >> 16);
}

// ---------------------------------------------------------------------------
// Projection via fp16 MFMA. Grid (128, 4): x-tile 128 pixels x one matrix.
// Wave = 128m x 32c; W-fragments live in registers (preloaded once);
// only x is staged in LDS (fp32 -> fp16).
//   by=0: K -> fp16 [n][128]       by=1: Q -> fp16 [n][128]
//   by=2: V -> bf16 [b][c][4096]   by=3: shortcut -> fp32 [n][128]
// ---------------------------------------------------------------------------
#define AP 48           // As row pitch in u16 (96 B: 16B-aligned rows)

__global__ __launch_bounds__(256, 2) void proj_kernel(
    const float* __restrict__ x,
    const float* __restrict__ Wk, const float* __restrict__ bk,
    const float* __restrict__ Wq, const float* __restrict__ bq,
    const float* __restrict__ Wv, const float* __restrict__ bv,
    const float* __restrict__ Ws, const float* __restrict__ bs,
    u16* __restrict__ Kh, u16* __restrict__ Qh,
    u16* __restrict__ Vt, float* __restrict__ Sc)
{
    __shared__ __align__(16) u16 As[128][AP];   // 12 KB

    const int tid = threadIdx.x;
    const int wv  = tid >> 6;
    const int l   = tid & 63;
    const int l15 = l & 15;
    const int l4  = l >> 4;
    const int by  = blockIdx.y;
    const int gm0 = blockIdx.x * 128;
    const int c0  = wv * 32;

    const float* W    = (by == 0) ? Wk : (by == 1) ? Wq : (by == 2) ? Wv : Ws;
    const float* bias = (by == 0) ? bk : (by == 1) ? bq : (by == 2) ? bv : bs;

    // ---- preload B fragments (W^T layout): Bf[ct][kc], lane -> W[k][c0+ct*16+l15]
    half8 Bf[2][8];
#pragma unroll
    for (int ct = 0; ct < 2; ++ct) {
        const int c = c0 + ct * 16 + l15;
#pragma unroll
        for (int kc = 0; kc < 8; ++kc) {
            const int kb = kc * 32 + l4 * 8;
#pragma unroll
            for (int j = 0; j < 8; ++j)
                Bf[ct][kc][j] = (_Float16)W[(size_t)(kb + j) * D + c];
        }
    }

    f32x4 acc[8][2];
#pragma unroll
    for (int mt = 0; mt < 8; ++mt) {
        acc[mt][0] = (f32x4){0.f, 0.f, 0.f, 0.f};
        acc[mt][1] = (f32x4){0.f, 0.f, 0.f, 0.f};
    }

    const int sm   = tid >> 1;          // staging row
    const int part = tid & 1;           // staging k-half

    for (int kc = 0; kc < 8; ++kc) {
        __syncthreads();
        // stage x[gm0..+128][kc*32..+32] -> fp16 LDS
        const float* src = x + (size_t)(gm0 + sm) * CC + kc * 32 + part * 16;
        const float4 f0 = ((const float4*)src)[0];
        const float4 f1 = ((const float4*)src)[1];
        const float4 f2 = ((const float4*)src)[2];
        const float4 f3 = ((const float4*)src)[3];
        half8 h0 = {(_Float16)f0.x, (_Float16)f0.y, (_Float16)f0.z, (_Float16)f0.w,
                    (_Float16)f1.x, (_Float16)f1.y, (_Float16)f1.z, (_Float16)f1.w};
        half8 h1 = {(_Float16)f2.x, (_Float16)f2.y, (_Float16)f2.z, (_Float16)f2.w,
                    (_Float16)f3.x, (_Float16)f3.y, (_Float16)f3.z, (_Float16)f3.w};
        *(half8*)&As[sm][part * 16]     = h0;
        *(half8*)&As[sm][part * 16 + 8] = h1;
        __syncthreads();

#pragma unroll
        for (int mt = 0; mt < 8; ++mt) {
            const half8 a = *(const half8*)&As[mt * 16 + l15][l4 * 8];
            acc[mt][0] = __builtin_amdgcn_mfma_f32_16x16x32_f16(a, Bf[0][kc], acc[mt][0], 0, 0, 0);
            acc[mt][1] = __builtin_amdgcn_mfma_f32_16x16x32_f16(a, Bf[1][kc], acc[mt][1], 0, 0, 0);
        }
    }

    // ---- epilogue
    const float bb[2] = {bias[c0 + l15], bias[c0 + 16 + l15]};

    if (by == 2) {
        // V: bf16 transposed [batch][c][m-in-batch], pack 4 consecutive m
        const int batch = gm0 >> 12;
        const int mb0   = (gm0 & 4095) + l4 * 4;
        u16* vb = Vt + (size_t)batch * (D * NPB);
#pragma unroll
        for (int mt = 0; mt < 8; ++mt) {
#pragma unroll
            for (int ct = 0; ct < 2; ++ct) {
                const int c = c0 + ct * 16 + l15;
                u16 t4[4];
#pragma unroll
                for (int r = 0; r < 4; ++r) t4[r] = f2bf(acc[mt][ct][r] + bb[ct]);
                *(uint2*)&vb[(size_t)c * NPB + mb0 + mt * 16] = *(const uint2*)t4;
            }
        }
    } else if (by == 3) {
#pragma unroll
        for (int mt = 0; mt < 8; ++mt)
#pragma unroll
            for (int ct = 0; ct < 2; ++ct)
#pragma unroll
                for (int r = 0; r < 4; ++r) {
                    const int m = gm0 + mt * 16 + l4 * 4 + r;
                    Sc[(size_t)m * D + c0 + ct * 16 + l15] = acc[mt][ct][r] + bb[ct];
                }
    } else {
        u16* O = (by == 0) ? Kh : Qh;
#pragma unroll
        for (int mt = 0; mt < 8; ++mt)
#pragma unroll
            for (int ct = 0; ct < 2; ++ct)
#pragma unroll
                for (int r = 0; r < 4; ++r) {
                    const int m = gm0 + mt * 16 + l4 * 4 + r;
                    const _Float16 v = (_Float16)(acc[mt][ct][r] + bb[ct]);
                    O[(size_t)m * D + c0 + ct * 16 + l15] =
                        __builtin_bit_cast(u16, v);
                }
    }
}

// ---------------------------------------------------------------------------
// Flash attention, ROUND-2 running-max online softmax (proven correct),
// K/Q fp16 (precision), P/V bf16. 512 blocks x 32 n-rows; 4 waves =
// 2 n-groups x 2 m-halves.
// ---------------------------------------------------------------------------
#define TM 32
#define QP 136          // Qs/Ks row pitch (u16)
#define VP 40           // Vs/Ps row pitch (u16)

__global__ __launch_bounds__(256) void attn_kernel(
    const u16* __restrict__ Kh, const u16* __restrict__ Qh,
    const u16* __restrict__ Vt, const float* __restrict__ Sc,
    float* __restrict__ out)
{
    __shared__ __align__(16) unsigned char smem[51712];
    u16 (*Ks)[QP]     = (u16(*)[QP])(smem);                 // 32 x 136 (fp16)
    u16 (*Qs)[TM][QP] = (u16(*)[TM][QP])(smem + 8704);      // 2 x 32 x 136 (fp16)
    u16 (*Vs)[D][VP]  = (u16(*)[D][VP])(smem + 26112);      // 2 x 128 x 40 (bf16)
    u16 (*Ps)[16][VP] = (u16(*)[16][VP])(smem + 46592);     // 4 x 16 x 40 (bf16)

    const int tid = threadIdx.x;
    const int wv  = tid >> 6;
    const int l   = tid & 63;
    const int l15 = l & 15;
    const int l4  = l >> 4;
    const int batch = blockIdx.x & 3;
    const int tile  = blockIdx.x >> 2;
    const int gr0   = batch * NPB + tile * 32;

    const int n16 = wv & 1;                 // n-group
    const int mh  = wv >> 1;                // m-half

    // ---- stage K tile (32 x 128 fp16)
    {
        const int row = tid >> 3, ch = tid & 7;
        const uint4* src = (const uint4*)(Kh + (size_t)(gr0 + row) * D + ch * 16);
        *(uint4*)&Ks[row][ch * 16]     = src[0];
        *(uint4*)&Ks[row][ch * 16 + 8] = src[1];
    }
    __syncthreads();

    half8 kf[4];
#pragma unroll
    for (int kc = 0; kc < 4; ++kc)
        kf[kc] = *(const half8*)&Ks[n16 * 16 + l15][kc * 32 + l4 * 8];

    f32x4 Oc[8];
#pragma unroll
    for (int ct = 0; ct < 8; ++ct) Oc[ct] = (f32x4){0.f, 0.f, 0.f, 0.f};
    float mold[4], lsum[4];
#pragma unroll
    for (int r = 0; r < 4; ++r) { mold[r] = -1e30f; lsum[r] = 0.f; }

    const u16* qsrc = Qh + (size_t)(batch * NPB + wv * 2048) * D;   // wv<2 only
    const u16* vsrc = Vt + (size_t)batch * NPB * D;                 // c-major

    for (int it = 0; it < 64; ++it) {
        __syncthreads();
        const int m0 = it * TM;
        if (wv < 2) {
            const u16* s = qsrc + (size_t)m0 * D + l15 * 8;
#pragma unroll
            for (int j = 0; j < 8; ++j) {
                const int row = j * 4 + l4;
                const uint4 v = *(const uint4*)(s + (size_t)row * D);
                *(uint4*)&Qs[wv][row][l15 * 8] = v;
            }
        } else {
            const int h = wv - 2;
            const u16* s = vsrc + (size_t)(h * 2048 + m0) + (l & 3) * 8;
#pragma unroll
            for (int j = 0; j < 8; ++j) {
                const int cc = j * 16 + (l >> 2);
                const uint4 v = *(const uint4*)(s + (size_t)cc * NPB);
                *(uint4*)&Vs[h][cc][(l & 3) * 8] = v;
            }
        }
        __syncthreads();

        // ---- S = K @ Q^T (fp16 MFMA)
        f32x4 sacc[2];
        sacc[0] = (f32x4){0.f, 0.f, 0.f, 0.f};
        sacc[1] = (f32x4){0.f, 0.f, 0.f, 0.f};
#pragma unroll
        for (int kc = 0; kc < 4; ++kc) {
#pragma unroll
            for (int mt = 0; mt < 2; ++mt) {
                const half8 qf =
                    *(const half8*)&Qs[mh][mt * 16 + l15][kc * 32 + l4 * 8];
                sacc[mt] = __builtin_amdgcn_mfma_f32_16x16x32_f16(
                    kf[kc], qf, sacc[mt], 0, 0, 0);
            }
        }

        // ---- online softmax (rows = l4*4+r, cols = mt*16 + l15)
        float rmax[4], rsum[4], pv0[4], pv1[4];
#pragma unroll
        for (int r = 0; r < 4; ++r) rmax[r] = fmaxf(sacc[0][r], sacc[1][r]);
#pragma unroll
        for (int mask = 1; mask <= 8; mask <<= 1)
#pragma unroll
            for (int r = 0; r < 4; ++r)
                rmax[r] = fmaxf(rmax[r], __shfl_xor(rmax[r], mask, 64));
#pragma unroll
        for (int r = 0; r < 4; ++r) {
            const float mnew  = fmaxf(mold[r], rmax[r]);
            const float alpha = __expf(mold[r] - mnew);
            mold[r] = mnew;
            const float s0 = __expf(sacc[0][r] - mnew);
            const float s1 = __expf(sacc[1][r] - mnew);
            pv0[r] = s0; pv1[r] = s1;
            rsum[r] = s0 + s1;
            lsum[r] *= alpha;
#pragma unroll
            for (int ct = 0; ct < 8; ++ct) Oc[ct][r] *= alpha;
        }
#pragma unroll
        for (int mask = 1; mask <= 8; mask <<= 1)
#pragma unroll
            for (int r = 0; r < 4; ++r)
                rsum[r] += __shfl_xor(rsum[r], mask, 64);
#pragma unroll
        for (int r = 0; r < 4; ++r) lsum[r] += rsum[r];

        // ---- P -> LDS (wave-local transpose to A-operand layout)
#pragma unroll
        for (int r = 0; r < 4; ++r) {
            Ps[wv][l4 * 4 + r][l15]      = f2bf(pv0[r]);
            Ps[wv][l4 * 4 + r][16 + l15] = f2bf(pv1[r]);
        }
        asm volatile("s_waitcnt lgkmcnt(0)" ::: "memory");

        const short8 pf = *(const short8*)&Ps[wv][l15][l4 * 8];
#pragma unroll
        for (int ct = 0; ct < 8; ++ct) {
            const short8 vf = *(const short8*)&Vs[mh][ct * 16 + l15][l4 * 8];
            Oc[ct] = __builtin_amdgcn_mfma_f32_16x16x32_bf16(pf, vf, Oc[ct], 0, 0, 0);
        }
    }

    // ---- combine the two m-halves (waves wv and wv^2 share rows)
    __syncthreads();
    float (*Obuf)[16][D] = (float(*)[16][D])(smem);         // aliases Ks/Qs
    float* cmbM = (float*)(smem + 26112);                   // aliases Vs
    float* cmbL = (float*)(smem + 26368);

    if (l15 == 0) {
#pragma unroll
        for (int r = 0; r < 4; ++r) {
            cmbM[wv * 16 + l4 * 4 + r] = mold[r];
            cmbL[wv * 16 + l4 * 4 + r] = lsum[r];
        }
    }
    if (mh == 1) {
#pragma unroll
        for (int ct = 0; ct < 8; ++ct)
#pragma unroll
            for (int r = 0; r < 4; ++r)
                Obuf[n16][l4 * 4 + r][ct * 16 + l15] = Oc[ct][r];
    }
    __syncthreads();

    if (mh == 0) {
        float f0[4], f1[4], invL[4];
#pragma unroll
        for (int r = 0; r < 4; ++r) {
            const int row = l4 * 4 + r;
            const float M1 = cmbM[(wv + 2) * 16 + row];
            const float L1 = cmbL[(wv + 2) * 16 + row];
            const float M  = fmaxf(mold[r], M1);
            const float a0 = __expf(mold[r] - M);
            const float a1 = __expf(M1 - M);
            f0[r] = a0; f1[r] = a1;
            invL[r] = 1.f / (lsum[r] * a0 + L1 * a1);
        }
#pragma unroll
        for (int ct = 0; ct < 8; ++ct) {
#pragma unroll
            for (int r = 0; r < 4; ++r) {
                const int row  = l4 * 4 + r;
                const int c    = ct * 16 + l15;
                const int grow = gr0 + n16 * 16 + row;
                const float val =
                    (Oc[ct][r] * f0[r] + Obuf[n16][row][c] * f1[r]) * invL[r]
                    + Sc[(size_t)grow * D + c];
                out[(size_t)grow * D + c] = val;
            }
        }
    }
}

extern "C" void kernel_launch(void* const* d_in, const int* in_sizes, int n_in,
                              void* d_out, int out_size, void* d_ws, size_t ws_size,
                              hipStream_t stream) {
    const float* x  = (const float*)d_in[0];
    const float* Wk = (const float*)d_in[1];
    const float* bk = (const float*)d_in[2];
    const float* Wq = (const float*)d_in[3];
    const float* bq = (const float*)d_in[4];
    const float* Wv = (const float*)d_in[5];
    const float* bv = (const float*)d_in[6];
    const float* Ws = (const float*)d_in[7];
    const float* bs = (const float*)d_in[8];
    float* out = (float*)d_out;

    u16*   Kh = (u16*)d_ws;                       // 4 MB fp16
    u16*   Qh = Kh + (size_t)BN * D;              // 4 MB fp16
    u16*   Vt = Qh + (size_t)BN * D;              // 4 MB bf16, [b][c][m]
    float* Sc = (float*)(Vt + (size_t)BN * D);    // 8 MB fp32

    proj_kernel<<<dim3(128, 4), 256, 0, stream>>>(x, Wk, bk, Wq, bq, Wv, bv,
                                                  Ws, bs, Kh, Qh, Vt, Sc);
    attn_kernel<<<512, 256, 0, stream>>>(Kh, Qh, Vt, Sc, out);
}

// Round 6
// 206.146 us; speedup vs baseline: 32.0107x; 1.1182x over previous
//
#include <hip/hip_runtime.h>
#include <math.h>

typedef unsigned short u16;
typedef __attribute__((ext_vector_type(8))) short    short8;   // 8 bf16
typedef __attribute__((ext_vector_type(8))) _Float16 half8;    // 8 fp16
typedef __attribute__((ext_vector_type(4))) float    f32x4;

#define BATCH 4
#define NPB   4096      // pixels per batch (H*W)
#define BN    16384     // BATCH * NPB
#define CC    256       // input channels
#define D     128       // output channels (C/2)

__device__ __forceinline__ u16 f2bf(float f) {
    unsigned u = __builtin_bit_cast(unsigned, f);
    u += 0x7fff + ((u >> 16) & 1);          // round-to-nearest-even
    return (u16)(u >> 16);
}

// 16-lane (DPP row) reductions on the VALU pipe — no LDS crossbar.
// dpp ctrl must be an integer constant expression -> template parameter.
template<int CTRL>
__device__ __forceinline__ float dpp_mov(float x) {
    return __builtin_bit_cast(float, __builtin_amdgcn_update_dpp(
        __builtin_bit_cast(int, x), __builtin_bit_cast(int, x),
        CTRL, 0xf, 0xf, false));
}
__device__ __forceinline__ float dpp_row_max(float x) {
    x = fmaxf(x, dpp_mov<0x128>(x));   // row_ror:8
    x = fmaxf(x, dpp_mov<0x124>(x));   // row_ror:4
    x = fmaxf(x, dpp_mov<0x122>(x));   // row_ror:2
    x = fmaxf(x, dpp_mov<0x121>(x));   // row_ror:1
    return x;
}
__device__ __forceinline__ float dpp_row_sum(float x) {
    x += dpp_mov<0x128>(x);
    x += dpp_mov<0x124>(x);
    x += dpp_mov<0x122>(x);
    x += dpp_mov<0x121>(x);
    return x;
}

// ---------------------------------------------------------------------------
// Projection via fp16 MFMA. Grid (128, 4): x-tile 128 pixels x one matrix.
//   by=0: K -> fp16 [n][128]       by=1: Q -> fp16 [n][128]
//   by=2: V -> bf16 [b][c][4096]   by=3: shortcut -> fp32 [n][128]
// by 0/1/3 use SWAPPED operands (D[c][m]) so each lane holds 4 consecutive c
// -> packed epilogue stores. by=2 keeps D[m][c] (lane holds 4 consecutive m).
// ---------------------------------------------------------------------------
#define AP 48           // As row pitch in u16 (96 B: 16B-aligned rows)

template<bool SWAP>
__device__ __forceinline__ void proj_loop(const float* __restrict__ x, int gm0,
                                          u16 (*As)[AP], half8 (&Bf)[2][8],
                                          f32x4 (&acc)[8][2], int tid)
{
    const int l15 = tid & 15, l4 = (tid & 63) >> 4;
    const int sm = tid >> 1, part = tid & 1;
    for (int kc = 0; kc < 8; ++kc) {
        __syncthreads();
        const float* src = x + (size_t)(gm0 + sm) * CC + kc * 32 + part * 16;
        const float4 f0 = ((const float4*)src)[0];
        const float4 f1 = ((const float4*)src)[1];
        const float4 f2 = ((const float4*)src)[2];
        const float4 f3 = ((const float4*)src)[3];
        half8 h0 = {(_Float16)f0.x, (_Float16)f0.y, (_Float16)f0.z, (_Float16)f0.w,
                    (_Float16)f1.x, (_Float16)f1.y, (_Float16)f1.z, (_Float16)f1.w};
        half8 h1 = {(_Float16)f2.x, (_Float16)f2.y, (_Float16)f2.z, (_Float16)f2.w,
                    (_Float16)f3.x, (_Float16)f3.y, (_Float16)f3.z, (_Float16)f3.w};
        *(half8*)&As[sm][part * 16]     = h0;
        *(half8*)&As[sm][part * 16 + 8] = h1;
        __syncthreads();

#pragma unroll
        for (int mt = 0; mt < 8; ++mt) {
            const half8 a = *(const half8*)&As[mt * 16 + l15][l4 * 8];
            if (SWAP) {
                acc[mt][0] = __builtin_amdgcn_mfma_f32_16x16x32_f16(Bf[0][kc], a, acc[mt][0], 0, 0, 0);
                acc[mt][1] = __builtin_amdgcn_mfma_f32_16x16x32_f16(Bf[1][kc], a, acc[mt][1], 0, 0, 0);
            } else {
                acc[mt][0] = __builtin_amdgcn_mfma_f32_16x16x32_f16(a, Bf[0][kc], acc[mt][0], 0, 0, 0);
                acc[mt][1] = __builtin_amdgcn_mfma_f32_16x16x32_f16(a, Bf[1][kc], acc[mt][1], 0, 0, 0);
            }
        }
    }
}

__global__ __launch_bounds__(256, 2) void proj_kernel(
    const float* __restrict__ x,
    const float* __restrict__ Wk, const float* __restrict__ bk,
    const float* __restrict__ Wq, const float* __restrict__ bq,
    const float* __restrict__ Wv, const float* __restrict__ bv,
    const float* __restrict__ Ws, const float* __restrict__ bs,
    u16* __restrict__ Kh, u16* __restrict__ Qh,
    u16* __restrict__ Vt, float* __restrict__ Sc)
{
    __shared__ __align__(16) u16 As[128][AP];   // 12 KB

    const int tid = threadIdx.x;
    const int wv  = tid >> 6;
    const int l   = tid & 63;
    const int l15 = l & 15;
    const int l4  = l >> 4;
    const int by  = blockIdx.y;
    const int gm0 = blockIdx.x * 128;
    const int c0  = wv * 32;

    const float* W    = (by == 0) ? Wk : (by == 1) ? Wq : (by == 2) ? Wv : Ws;
    const float* bias = (by == 0) ? bk : (by == 1) ? bq : (by == 2) ? bv : bs;

    // ---- preload W fragments: Bf[ct][kc], lane -> W[k][c0+ct*16+l15]
    half8 Bf[2][8];
#pragma unroll
    for (int ct = 0; ct < 2; ++ct) {
        const int c = c0 + ct * 16 + l15;
#pragma unroll
        for (int kc = 0; kc < 8; ++kc) {
            const int kb = kc * 32 + l4 * 8;
#pragma unroll
            for (int j = 0; j < 8; ++j)
                Bf[ct][kc][j] = (_Float16)W[(size_t)(kb + j) * D + c];
        }
    }

    f32x4 acc[8][2];
#pragma unroll
    for (int mt = 0; mt < 8; ++mt) {
        acc[mt][0] = (f32x4){0.f, 0.f, 0.f, 0.f};
        acc[mt][1] = (f32x4){0.f, 0.f, 0.f, 0.f};
    }

    if (by == 2) {
        proj_loop<false>(x, gm0, As, Bf, acc, tid);
        // V: D[m][c] (col=lane&15 -> c, rows -> m). bf16 transposed
        // [batch][c][m-in-batch], pack 4 consecutive m.
        const float bb[2] = {bias[c0 + l15], bias[c0 + 16 + l15]};
        const int batch = gm0 >> 12;
        const int mb0   = (gm0 & 4095) + l4 * 4;
        u16* vb = Vt + (size_t)batch * (D * NPB);
#pragma unroll
        for (int mt = 0; mt < 8; ++mt) {
#pragma unroll
            for (int ct = 0; ct < 2; ++ct) {
                const int c = c0 + ct * 16 + l15;
                u16 t4[4];
#pragma unroll
                for (int r = 0; r < 4; ++r) t4[r] = f2bf(acc[mt][ct][r] + bb[ct]);
                *(uint2*)&vb[(size_t)c * NPB + mb0 + mt * 16] = *(const uint2*)t4;
            }
        }
    } else {
        proj_loop<true>(x, gm0, As, Bf, acc, tid);
        // swapped: D[c][m] — lane holds c = c0+ct*16+l4*4+r, m = gm0+mt*16+l15
        float bb2[2][4];
#pragma unroll
        for (int ct = 0; ct < 2; ++ct)
#pragma unroll
            for (int r = 0; r < 4; ++r)
                bb2[ct][r] = bias[c0 + ct * 16 + l4 * 4 + r];

        if (by == 3) {
#pragma unroll
            for (int mt = 0; mt < 8; ++mt) {
                const int m = gm0 + mt * 16 + l15;
#pragma unroll
                for (int ct = 0; ct < 2; ++ct) {
                    float4 v;
                    v.x = acc[mt][ct][0] + bb2[ct][0];
                    v.y = acc[mt][ct][1] + bb2[ct][1];
                    v.z = acc[mt][ct][2] + bb2[ct][2];
                    v.w = acc[mt][ct][3] + bb2[ct][3];
                    *(float4*)&Sc[(size_t)m * D + c0 + ct * 16 + l4 * 4] = v;
                }
            }
        } else {
            u16* O = (by == 0) ? Kh : Qh;
#pragma unroll
            for (int mt = 0; mt < 8; ++mt) {
                const int m = gm0 + mt * 16 + l15;
#pragma unroll
                for (int ct = 0; ct < 2; ++ct) {
                    _Float16 t4[4];
#pragma unroll
                    for (int r = 0; r < 4; ++r)
                        t4[r] = (_Float16)(acc[mt][ct][r] + bb2[ct][r]);
                    *(uint2*)&O[(size_t)m * D + c0 + ct * 16 + l4 * 4] =
                        *(const uint2*)t4;
                }
            }
        }
    }
}

// ---------------------------------------------------------------------------
// Flash attention, running-max online softmax with DPP row reductions
// (no LDS-crossbar shuffles in the hot loop), K/Q fp16, P/V bf16.
// 512 blocks x 32 n-rows; 4 waves = 2 n-groups x 2 m-halves.
// ---------------------------------------------------------------------------
#define TM 32
#define QP 136          // Qs/Ks row pitch (u16)
#define VP 40           // Vs/Ps row pitch (u16)

__global__ __launch_bounds__(256) void attn_kernel(
    const u16* __restrict__ Kh, const u16* __restrict__ Qh,
    const u16* __restrict__ Vt, const float* __restrict__ Sc,
    float* __restrict__ out)
{
    __shared__ __align__(16) unsigned char smem[51712];
    u16 (*Ks)[QP]     = (u16(*)[QP])(smem);                 // 32 x 136 (fp16)
    u16 (*Qs)[TM][QP] = (u16(*)[TM][QP])(smem + 8704);      // 2 x 32 x 136 (fp16)
    u16 (*Vs)[D][VP]  = (u16(*)[D][VP])(smem + 26112);      // 2 x 128 x 40 (bf16)
    u16 (*Ps)[16][VP] = (u16(*)[16][VP])(smem + 46592);     // 4 x 16 x 40 (bf16)

    const int tid = threadIdx.x;
    const int wv  = tid >> 6;
    const int l   = tid & 63;
    const int l15 = l & 15;
    const int l4  = l >> 4;
    const int batch = blockIdx.x & 3;
    const int tile  = blockIdx.x >> 2;
    const int gr0   = batch * NPB + tile * 32;

    const int n16 = wv & 1;                 // n-group
    const int mh  = wv >> 1;                // m-half

    // ---- stage K tile (32 x 128 fp16)
    {
        const int row = tid >> 3, ch = tid & 7;
        const uint4* src = (const uint4*)(Kh + (size_t)(gr0 + row) * D + ch * 16);
        *(uint4*)&Ks[row][ch * 16]     = src[0];
        *(uint4*)&Ks[row][ch * 16 + 8] = src[1];
    }
    __syncthreads();

    half8 kf[4];
#pragma unroll
    for (int kc = 0; kc < 4; ++kc)
        kf[kc] = *(const half8*)&Ks[n16 * 16 + l15][kc * 32 + l4 * 8];

    f32x4 Oc[8];
#pragma unroll
    for (int ct = 0; ct < 8; ++ct) Oc[ct] = (f32x4){0.f, 0.f, 0.f, 0.f};
    float mold[4], lsum[4];
#pragma unroll
    for (int r = 0; r < 4; ++r) { mold[r] = -1e30f; lsum[r] = 0.f; }

    const u16* qsrc = Qh + (size_t)(batch * NPB + wv * 2048) * D;   // wv<2 only
    const u16* vsrc = Vt + (size_t)batch * NPB * D;                 // c-major

    for (int it = 0; it < 64; ++it) {
        __syncthreads();
        const int m0 = it * TM;
        if (wv < 2) {
            const u16* s = qsrc + (size_t)m0 * D + l15 * 8;
#pragma unroll
            for (int j = 0; j < 8; ++j) {
                const int row = j * 4 + l4;
                const uint4 v = *(const uint4*)(s + (size_t)row * D);
                *(uint4*)&Qs[wv][row][l15 * 8] = v;
            }
        } else {
            const int h = wv - 2;
            const u16* s = vsrc + (size_t)(h * 2048 + m0) + (l & 3) * 8;
#pragma unroll
            for (int j = 0; j < 8; ++j) {
                const int cc = j * 16 + (l >> 2);
                const uint4 v = *(const uint4*)(s + (size_t)cc * NPB);
                *(uint4*)&Vs[h][cc][(l & 3) * 8] = v;
            }
        }
        __syncthreads();

        // ---- S = K @ Q^T (fp16 MFMA)
        f32x4 sacc[2];
        sacc[0] = (f32x4){0.f, 0.f, 0.f, 0.f};
        sacc[1] = (f32x4){0.f, 0.f, 0.f, 0.f};
#pragma unroll
        for (int kc = 0; kc < 4; ++kc) {
#pragma unroll
            for (int mt = 0; mt < 2; ++mt) {
                const half8 qf =
                    *(const half8*)&Qs[mh][mt * 16 + l15][kc * 32 + l4 * 8];
                sacc[mt] = __builtin_amdgcn_mfma_f32_16x16x32_f16(
                    kf[kc], qf, sacc[mt], 0, 0, 0);
            }
        }

        // ---- online softmax: DPP row-max (VALU), per-lane deferred sum
#pragma unroll
        for (int r = 0; r < 4; ++r) {
            const float rmax = dpp_row_max(fmaxf(sacc[0][r], sacc[1][r]));
            const float mnew  = fmaxf(mold[r], rmax);
            const float alpha = __expf(mold[r] - mnew);
            mold[r] = mnew;
            const float p0 = __expf(sacc[0][r] - mnew);
            const float p1 = __expf(sacc[1][r] - mnew);
            lsum[r] = lsum[r] * alpha + p0 + p1;
#pragma unroll
            for (int ct = 0; ct < 8; ++ct) Oc[ct][r] *= alpha;
            Ps[wv][l4 * 4 + r][l15]      = f2bf(p0);
            Ps[wv][l4 * 4 + r][16 + l15] = f2bf(p1);
        }
        asm volatile("s_waitcnt lgkmcnt(0)" ::: "memory");

        const short8 pf = *(const short8*)&Ps[wv][l15][l4 * 8];
#pragma unroll
        for (int ct = 0; ct < 8; ++ct) {
            const short8 vf = *(const short8*)&Vs[mh][ct * 16 + l15][l4 * 8];
            Oc[ct] = __builtin_amdgcn_mfma_f32_16x16x32_bf16(pf, vf, Oc[ct], 0, 0, 0);
        }
    }

    // ---- final per-row sum across the 16 column-lanes (once, DPP)
#pragma unroll
    for (int r = 0; r < 4; ++r) lsum[r] = dpp_row_sum(lsum[r]);

    // ---- combine the two m-halves (waves wv and wv^2 share rows)
    __syncthreads();
    float (*Obuf)[16][D] = (float(*)[16][D])(smem);         // aliases Ks/Qs
    float* cmbM = (float*)(smem + 26112);                   // aliases Vs
    float* cmbL = (float*)(smem + 26368);

    if (l15 == 0) {
#pragma unroll
        for (int r = 0; r < 4; ++r) {
            cmbM[wv * 16 + l4 * 4 + r] = mold[r];
            cmbL[wv * 16 + l4 * 4 + r] = lsum[r];
        }
    }
    if (mh == 1) {
#pragma unroll
        for (int ct = 0; ct < 8; ++ct)
#pragma unroll
            for (int r = 0; r < 4; ++r)
                Obuf[n16][l4 * 4 + r][ct * 16 + l15] = Oc[ct][r];
    }
    __syncthreads();

    if (mh == 0) {
        float f0[4], f1[4], invL[4];
#pragma unroll
        for (int r = 0; r < 4; ++r) {
            const int row = l4 * 4 + r;
            const float M1 = cmbM[(wv + 2) * 16 + row];
            const float L1 = cmbL[(wv + 2) * 16 + row];
            const float M  = fmaxf(mold[r], M1);
            const float a0 = __expf(mold[r] - M);
            const float a1 = __expf(M1 - M);
            f0[r] = a0; f1[r] = a1;
            invL[r] = 1.f / (lsum[r] * a0 + L1 * a1);
        }
#pragma unroll
        for (int ct = 0; ct < 8; ++ct) {
#pragma unroll
            for (int r = 0; r < 4; ++r) {
                const int row  = l4 * 4 + r;
                const int c    = ct * 16 + l15;
                const int grow = gr0 + n16 * 16 + row;
                const float val =
                    (Oc[ct][r] * f0[r] + Obuf[n16][row][c] * f1[r]) * invL[r]
                    + Sc[(size_t)grow * D + c];
                out[(size_t)grow * D + c] = val;
            }
        }
    }
}

extern "C" void kernel_launch(void* const* d_in, const int* in_sizes, int n_in,
                              void* d_out, int out_size, void* d_ws, size_t ws_size,
                              hipStream_t stream) {
    const float* x  = (const float*)d_in[0];
    const float* Wk = (const float*)d_in[1];
    const float* bk = (const float*)d_in[2];
    const float* Wq = (const float*)d_in[3];
    const float* bq = (const float*)d_in[4];
    const float* Wv = (const float*)d_in[5];
    const float* bv = (const float*)d_in[6];
    const float* Ws = (const float*)d_in[7];
    const float* bs = (const float*)d_in[8];
    float* out = (float*)d_out;

    u16*   Kh = (u16*)d_ws;                       // 4 MB fp16
    u16*   Qh = Kh + (size_t)BN * D;              // 4 MB fp16
    u16*   Vt = Qh + (size_t)BN * D;              // 4 MB bf16, [b][c][m]
    float* Sc = (float*)(Vt + (size_t)BN * D);    // 8 MB fp32

    proj_kernel<<<dim3(128, 4), 256, 0, stream>>>(x, Wk, bk, Wq, bq, Wv, bv,
                                                  Ws, bs, Kh, Qh, Vt, Sc);
    attn_kernel<<<512, 256, 0, stream>>>(Kh, Qh, Vt, Sc, out);
}